// Round 11
// baseline (516.798 us; speedup 1.0000x reference)
//
#include <hip/hip_runtime.h>
#include <hip/hip_bf16.h>

#define HID 128

typedef __attribute__((ext_vector_type(8))) short short8;
typedef __attribute__((ext_vector_type(4))) float f32x4;

__device__ __forceinline__ unsigned short f2bf(float f) {
    unsigned int u = __builtin_bit_cast(unsigned int, f);
    u += 0x7FFFu + ((u >> 16) & 1u);
    return (unsigned short)(u >> 16);
}
__device__ __forceinline__ float bf2f(unsigned short h) {
    unsigned int u = ((unsigned int)h) << 16;
    return __builtin_bit_cast(float, u);
}

// ---------------- prep: W[k][128] f32 -> fragment order Wf[ks][nt][lane][j] bf16 ----------------
__global__ void prep_w(const float* __restrict__ W, unsigned short* __restrict__ Wf, int nks) {
    int t = blockIdx.x * 256 + threadIdx.x;
    if (t >= nks * 8 * 64) return;
    int lane = t & 63, nt = (t >> 6) & 7, ks = t >> 9;
    int kb  = ks * 32 + ((lane >> 4) << 3);
    int col = (nt << 4) + (lane & 15);
    union { unsigned short u[8]; uint4 q; } p;
    #pragma unroll
    for (int j = 0; j < 8; ++j) p.u[j] = f2bf(W[(size_t)(kb + j) * 128 + col]);
    *(uint4*)(Wf + (size_t)t * 8) = p.q;
}

// hi/lo split fragments for near-fp32 node GEMMs
__global__ void prep_w_split(const float* __restrict__ W,
                             unsigned short* __restrict__ Wh,
                             unsigned short* __restrict__ Wl, int nks) {
    int t = blockIdx.x * 256 + threadIdx.x;
    if (t >= nks * 8 * 64) return;
    int lane = t & 63, nt = (t >> 6) & 7, ks = t >> 9;
    int kb  = ks * 32 + ((lane >> 4) << 3);
    int col = (nt << 4) + (lane & 15);
    union { unsigned short u[8]; uint4 q; } ph, pl;
    #pragma unroll
    for (int j = 0; j < 8; ++j) {
        float w = W[(size_t)(kb + j) * 128 + col];
        unsigned short h = f2bf(w);
        ph.u[j] = h;
        pl.u[j] = f2bf(w - bf2f(h));
    }
    *(uint4*)(Wh + (size_t)t * 8) = ph.q;
    *(uint4*)(Wl + (size_t)t * 8) = pl.q;
}

// ---------------- composed weights: C = Wm2 @ Bpart (both 128x128 f32) ----------------
__global__ void compose_k(const float* __restrict__ A, const float* __restrict__ B,
                          float* __restrict__ C) {
    int t = blockIdx.x * 256 + threadIdx.x;
    if (t >= 128 * 128) return;
    int i = t >> 7, j = t & 127;
    float s = 0.f;
    for (int k = 0; k < 128; ++k) s = fmaf(A[i * 128 + k], B[(size_t)k * 128 + j], s);
    C[t] = s;
}
__global__ void bias_comp_k(const float* __restrict__ b2, const float* __restrict__ B,
                            float* __restrict__ bc) {
    int j = threadIdx.x;
    if (j >= 128) return;
    float s = 0.f;
    for (int k = 0; k < 128; ++k) s = fmaf(b2[k], B[(size_t)k * 128 + j], s);
    bc[j] = s;
}
// stacked [256x128]: rows 0-127 from Wtop, rows 128-255 from C
__global__ void stack_k(const float* __restrict__ Wtop, const float* __restrict__ C,
                        float* __restrict__ S) {
    int t = blockIdx.x * 256 + threadIdx.x;
    if (t >= 256 * 128) return;
    int r = t >> 7, c = t & 127;
    S[t] = (r < 128) ? Wtop[(size_t)r * 128 + c] : C[(size_t)(r - 128) * 128 + c];
}

// ---------------- counting sort by dst (cnt/cur + materialized srcS, eaS) ----------------
__global__ void hist_k(const int* __restrict__ ei, unsigned* __restrict__ cnt, int E) {
    int e = blockIdx.x * 256 + threadIdx.x;
    if (e < E) atomicAdd(&cnt[ei[E + e]], 1u);
}

__global__ void scan_k(const unsigned* __restrict__ cnt, unsigned* __restrict__ cur, int n) {
    __shared__ unsigned wsum[16];
    int tid = threadIdx.x, lane = tid & 63, w = tid >> 6;
    unsigned carry = 0;
    for (int base = 0; base < n; base += 1024) {
        int i = base + tid;
        unsigned v = (i < n) ? cnt[i] : 0u;
        unsigned s = v;
        #pragma unroll
        for (int off = 1; off < 64; off <<= 1) {
            unsigned t = __shfl_up(s, off);
            if (lane >= off) s += t;
        }
        if (lane == 63) wsum[w] = s;
        __syncthreads();
        if (tid < 16) {
            unsigned t = wsum[tid];
            #pragma unroll
            for (int off = 1; off < 16; off <<= 1) {
                unsigned u = __shfl_up(t, off);
                if (tid >= off) t += u;
            }
            wsum[tid] = t;
        }
        __syncthreads();
        unsigned woff = (w == 0) ? 0u : wsum[w - 1];
        if (i < n) cur[i] = carry + woff + s - v;
        unsigned tot = wsum[15];
        __syncthreads();
        carry += tot;
    }
}

__global__ void scatter_k(const int* __restrict__ ei, const float* __restrict__ ea,
                          unsigned* __restrict__ cur,
                          int* __restrict__ srcS, float* __restrict__ eaS, int E) {
    int e = blockIdx.x * 256 + threadIdx.x;
    if (e >= E) return;
    int d = ei[E + e];
    unsigned pos = atomicAdd(&cur[d], 1u);
    srcS[pos] = ei[e];
    eaS[(size_t)pos * 3 + 0] = ea[(size_t)e * 3 + 0];
    eaS[(size_t)pos * 3 + 1] = ea[(size_t)e * 3 + 1];
    eaS[(size_t)pos * 3 + 2] = ea[(size_t)e * 3 + 2];
}

// ---------------- S1 = x@W1[:128], T = x@W1[128:256] (bf16 out) ----------------
__global__ __launch_bounds__(256, 2)
void s1t_gemm(const float* __restrict__ x, const unsigned short* __restrict__ W1f,
              unsigned short* __restrict__ S1b, unsigned short* __restrict__ Tb, int N)
{
    const int lane = threadIdx.x & 63;
    const int wid  = threadIdx.x >> 6;
    const int n0   = (blockIdx.x * 4 + wid) * 16;
    if (n0 >= N) return;
    const int arow = lane & 15;
    const int g4   = lane >> 4;

    int nr = n0 + arow; if (nr >= N) nr = N - 1;
    const float* px = x + (size_t)nr * 128 + g4 * 8;

    short8 af[4];
    #pragma unroll
    for (int ks = 0; ks < 4; ++ks) {
        float4 v0 = *(const float4*)(px + ks * 32);
        float4 v1 = *(const float4*)(px + ks * 32 + 4);
        float v[8] = { v0.x, v0.y, v0.z, v0.w, v1.x, v1.y, v1.z, v1.w };
        #pragma unroll
        for (int j = 0; j < 8; ++j) af[ks][j] = (short)f2bf(v[j]);
    }

    f32x4 s1[8], tt[8];
    #pragma unroll
    for (int i = 0; i < 8; ++i) { s1[i] = (f32x4)0.f; tt[i] = (f32x4)0.f; }
    #pragma unroll
    for (int ks = 0; ks < 4; ++ks) {
        #pragma unroll
        for (int nt = 0; nt < 8; ++nt) {
            short8 b1 = *(const short8*)(W1f + (size_t)((ks * 8 + nt) * 64 + lane) * 8);
            short8 b2 = *(const short8*)(W1f + (size_t)(((ks + 4) * 8 + nt) * 64 + lane) * 8);
            s1[nt] = __builtin_amdgcn_mfma_f32_16x16x32_bf16(af[ks], b1, s1[nt], 0, 0, 0);
            tt[nt] = __builtin_amdgcn_mfma_f32_16x16x32_bf16(af[ks], b2, tt[nt], 0, 0, 0);
        }
    }
    #pragma unroll
    for (int nt = 0; nt < 8; ++nt) {
        int col = nt * 16 + arow;
        #pragma unroll
        for (int r = 0; r < 4; ++r) {
            int node = n0 + g4 * 4 + r;
            if (node < N) {
                S1b[(size_t)node * 128 + col] = f2bf(s1[nt][r]);
                Tb [(size_t)node * 128 + col] = f2bf(tt[nt][r]);
            }
        }
    }
}

// ---------------- CSR edge kernel: HS[d] = sum_e relu(S1[src]+T[d]+ea.W1tail+b1) ----------------
// One wave per dst at a time; zero atomics; plain stores.
__global__ __launch_bounds__(256, 8)
void csr_edge_k(const unsigned short* __restrict__ S1b, const unsigned short* __restrict__ Tb,
                const int* __restrict__ srcS, const float* __restrict__ eaS,
                const unsigned* __restrict__ cnt, const unsigned* __restrict__ cur,
                const float* __restrict__ W1tail, const float* __restrict__ bm1,
                float* __restrict__ HS, int N)
{
    const int lane = threadIdx.x & 63;
    const int wid  = threadIdx.x >> 6;
    const int gw   = blockIdx.x * 4 + wid;
    const int stride = gridDim.x * 4;
    const int c2 = lane * 2;

    const float w00 = W1tail[c2],       w01 = W1tail[c2 + 1];
    const float w10 = W1tail[128 + c2], w11 = W1tail[128 + c2 + 1];
    const float w20 = W1tail[256 + c2], w21 = W1tail[256 + c2 + 1];
    const float b0  = bm1[c2],          b1v = bm1[c2 + 1];

    for (int d = gw; d < N; d += stride) {
        int e1 = (int)cur[d];
        int c  = (int)cnt[d];
        int e0 = e1 - c;
        unsigned tv = *(const unsigned*)(Tb + (size_t)d * 128 + c2);
        float t0 = bf2f((unsigned short)(tv & 0xffff)) + b0;
        float t1 = bf2f((unsigned short)(tv >> 16))    + b1v;
        float a0 = 0.f, a1 = 0.f;
        for (int e = e0; e < e1; ++e) {
            int s = srcS[e];
            float x0 = eaS[(size_t)e * 3 + 0];
            float x1 = eaS[(size_t)e * 3 + 1];
            float x2 = eaS[(size_t)e * 3 + 2];
            unsigned sv = *(const unsigned*)(S1b + (size_t)s * 128 + c2);
            float h0 = bf2f((unsigned short)(sv & 0xffff)) + t0;
            float h1 = bf2f((unsigned short)(sv >> 16))    + t1;
            h0 = fmaf(x0, w00, h0); h0 = fmaf(x1, w10, h0); h0 = fmaf(x2, w20, h0);
            h1 = fmaf(x0, w01, h1); h1 = fmaf(x1, w11, h1); h1 = fmaf(x2, w21, h1);
            a0 += fmaxf(h0, 0.f);
            a1 += fmaxf(h1, 0.f);
        }
        float2 o; o.x = a0; o.y = a1;
        *(float2*)(HS + (size_t)d * 128 + c2) = o;
    }
}

// tier-C fallback: per-edge atomics, no sort arrays (HS must be pre-zeroed)
__global__ __launch_bounds__(256, 8)
void atomic_edge_k(const unsigned short* __restrict__ S1b, const unsigned short* __restrict__ Tb,
                   const int* __restrict__ ei, const float* __restrict__ ea,
                   const float* __restrict__ W1tail, const float* __restrict__ bm1,
                   float* __restrict__ HS, int E)
{
    const int lane = threadIdx.x & 63;
    const int wid  = threadIdx.x >> 6;
    const int gw   = blockIdx.x * 4 + wid;
    const int stride = gridDim.x * 4;
    const int c2 = lane * 2;

    const float w00 = W1tail[c2],       w01 = W1tail[c2 + 1];
    const float w10 = W1tail[128 + c2], w11 = W1tail[128 + c2 + 1];
    const float w20 = W1tail[256 + c2], w21 = W1tail[256 + c2 + 1];
    const float b0  = bm1[c2],          b1v = bm1[c2 + 1];

    for (int e = gw; e < E; e += stride) {
        int s = ei[e], d = ei[E + e];
        float x0 = ea[(size_t)e * 3 + 0];
        float x1 = ea[(size_t)e * 3 + 1];
        float x2 = ea[(size_t)e * 3 + 2];
        unsigned tv = *(const unsigned*)(Tb + (size_t)d * 128 + c2);
        unsigned sv = *(const unsigned*)(S1b + (size_t)s * 128 + c2);
        float h0 = bf2f((unsigned short)(sv & 0xffff)) + bf2f((unsigned short)(tv & 0xffff)) + b0;
        float h1 = bf2f((unsigned short)(sv >> 16))    + bf2f((unsigned short)(tv >> 16))    + b1v;
        h0 = fmaf(x0, w00, h0); h0 = fmaf(x1, w10, h0); h0 = fmaf(x2, w20, h0);
        h1 = fmaf(x0, w01, h1); h1 = fmaf(x1, w11, h1); h1 = fmaf(x2, w21, h1);
        unsafeAtomicAdd(HS + (size_t)d * 128 + c2,     fmaxf(h0, 0.f));
        unsafeAtomicAdd(HS + (size_t)d * 128 + c2 + 1, fmaxf(h1, 0.f));
    }
}

// ---------------- Node kernel: [x|HS] @ stacked-composed weights + deg bias + LN ----------------
__global__ __launch_bounds__(256, 3)
void node_mfma(const float* __restrict__ x,
               const float* __restrict__ HS,
               const unsigned* __restrict__ cnt,
               const float* __restrict__ bcg, const float* __restrict__ bcu,
               const unsigned short* __restrict__ WgH, const unsigned short* __restrict__ WgL,
               const unsigned short* __restrict__ Wu1H, const unsigned short* __restrict__ Wu1L,
               const unsigned short* __restrict__ Wu2H, const unsigned short* __restrict__ Wu2L,
               const float* __restrict__ bg, const float* __restrict__ bu1,
               const float* __restrict__ bu2,
               const float* __restrict__ gamma, const float* __restrict__ beta,
               float* __restrict__ out, int N)
{
    __shared__ alignas(16) char Hs[4][8192];

    const int tid  = threadIdx.x;
    const int lane = tid & 63;
    const int wid  = tid >> 6;
    const int n0   = (blockIdx.x * 4 + wid) * 16;
    if (n0 >= N) return;

    const int arow = lane & 15;
    const int g4   = lane >> 4;

    int nr = n0 + arow; if (nr >= N) nr = N - 1;
    const float* px = x  + (size_t)nr * 128 + g4 * 8;
    const float* pa = HS + (size_t)nr * 128 + g4 * 8;

    short8 ah[8], al[8];
    #pragma unroll
    for (int ks = 0; ks < 8; ++ks) {
        const float* p = (ks < 4) ? (px + ks * 32) : (pa + (ks - 4) * 32);
        float4 v0 = *(const float4*)p;
        float4 v1 = *(const float4*)(p + 4);
        float v[8] = { v0.x, v0.y, v0.z, v0.w, v1.x, v1.y, v1.z, v1.w };
        #pragma unroll
        for (int j = 0; j < 8; ++j) {
            unsigned short h = f2bf(v[j]);
            ah[ks][j] = (short)h;
            al[ks][j] = (short)f2bf(v[j] - bf2f(h));
        }
    }

    float degf[4];
    #pragma unroll
    for (int r = 0; r < 4; ++r) {
        int node = n0 + g4 * 4 + r;
        degf[r] = (node < N) ? (float)cnt[node] : 0.f;
    }

    f32x4 ga[8];
    #pragma unroll
    for (int i = 0; i < 8; ++i) ga[i] = (f32x4)0.f;
    #pragma unroll
    for (int ks = 0; ks < 8; ++ks) {
        #pragma unroll
        for (int nt = 0; nt < 8; ++nt) {
            size_t o = (size_t)((ks * 8 + nt) * 64 + lane) * 8;
            short8 bh = *(const short8*)(WgH + o);
            short8 bl = *(const short8*)(WgL + o);
            ga[nt] = __builtin_amdgcn_mfma_f32_16x16x32_bf16(ah[ks], bh, ga[nt], 0, 0, 0);
            ga[nt] = __builtin_amdgcn_mfma_f32_16x16x32_bf16(al[ks], bh, ga[nt], 0, 0, 0);
            ga[nt] = __builtin_amdgcn_mfma_f32_16x16x32_bf16(ah[ks], bl, ga[nt], 0, 0, 0);
        }
    }

    f32x4 ua[8];
    #pragma unroll
    for (int i = 0; i < 8; ++i) ua[i] = (f32x4)0.f;
    #pragma unroll
    for (int ks = 0; ks < 8; ++ks) {
        #pragma unroll
        for (int nt = 0; nt < 8; ++nt) {
            size_t o = (size_t)((ks * 8 + nt) * 64 + lane) * 8;
            short8 bh = *(const short8*)(Wu1H + o);
            short8 bl = *(const short8*)(Wu1L + o);
            ua[nt] = __builtin_amdgcn_mfma_f32_16x16x32_bf16(ah[ks], bh, ua[nt], 0, 0, 0);
            ua[nt] = __builtin_amdgcn_mfma_f32_16x16x32_bf16(al[ks], bh, ua[nt], 0, 0, 0);
            ua[nt] = __builtin_amdgcn_mfma_f32_16x16x32_bf16(ah[ks], bl, ua[nt], 0, 0, 0);
        }
    }

    // + deg * composed-bias terms (agg's b2 contribution through composed mats)
    #pragma unroll
    for (int nt = 0; nt < 8; ++nt) {
        int col = nt * 16 + arow;
        float bgc = bcg[col], buc = bcu[col];
        #pragma unroll
        for (int r = 0; r < 4; ++r) {
            ga[nt][r] = fmaf(degf[r], bgc, ga[nt][r]);
            ua[nt][r] = fmaf(degf[r], buc, ua[nt][r]);
        }
    }

    #pragma unroll
    for (int nt = 0; nt < 8; ++nt) {
        int col = nt * 16 + arow;
        float b1 = bu1[col];
        #pragma unroll
        for (int r = 0; r < 4; ++r) {
            int row = g4 * 4 + r;
            float u = fmaxf(ua[nt][r] + b1, 0.f);
            unsigned short h = f2bf(u);
            unsigned short l = f2bf(u - bf2f(h));
            unsigned int pk = (unsigned int)h | ((unsigned int)l << 16);
            *(unsigned int*)(&Hs[wid][row * 512 + ((col * 4) ^ ((row & 15) << 4))]) = pk;
        }
    }

    #pragma unroll
    for (int nt = 0; nt < 8; ++nt) {
        int col = nt * 16 + arow;
        float b = bg[col];
        #pragma unroll
        for (int r = 0; r < 4; ++r)
            ga[nt][r] = 1.f / (1.f + expf(-(ga[nt][r] + b)));
    }
    __syncthreads();

    f32x4 u2[8];
    #pragma unroll
    for (int i = 0; i < 8; ++i) u2[i] = (f32x4)0.f;
    #pragma unroll
    for (int ks = 0; ks < 4; ++ks) {
        int b0 = ks * 128 + g4 * 32;
        unsigned int q0[4], q1[4];
        *(uint4*)q0 = *(const uint4*)(&Hs[wid][arow * 512 + ( b0       ^ (arow << 4))]);
        *(uint4*)q1 = *(const uint4*)(&Hs[wid][arow * 512 + ((b0 + 16) ^ (arow << 4))]);
        short8 a2h, a2l;
        #pragma unroll
        for (int j = 0; j < 4; ++j) {
            a2h[j]     = (short)(q0[j] & 0xffff);
            a2l[j]     = (short)(q0[j] >> 16);
            a2h[4 + j] = (short)(q1[j] & 0xffff);
            a2l[4 + j] = (short)(q1[j] >> 16);
        }
        #pragma unroll
        for (int nt = 0; nt < 8; ++nt) {
            size_t o = (size_t)((ks * 8 + nt) * 64 + lane) * 8;
            short8 bh = *(const short8*)(Wu2H + o);
            short8 bl = *(const short8*)(Wu2L + o);
            u2[nt] = __builtin_amdgcn_mfma_f32_16x16x32_bf16(a2h, bh, u2[nt], 0, 0, 0);
            u2[nt] = __builtin_amdgcn_mfma_f32_16x16x32_bf16(a2l, bh, u2[nt], 0, 0, 0);
            u2[nt] = __builtin_amdgcn_mfma_f32_16x16x32_bf16(a2h, bl, u2[nt], 0, 0, 0);
        }
    }

    float s[4]  = {0.f, 0.f, 0.f, 0.f};
    float ss[4] = {0.f, 0.f, 0.f, 0.f};
    #pragma unroll
    for (int nt = 0; nt < 8; ++nt) {
        int col = nt * 16 + arow;
        float b2 = bu2[col];
        #pragma unroll
        for (int r = 0; r < 4; ++r) {
            int node = n0 + g4 * 4 + r;
            float xv = x[(size_t)node * 128 + col];
            float g  = ga[nt][r];
            float o  = g * (u2[nt][r] + b2) + (1.f - g) * xv;
            u2[nt][r] = o;
            s[r]  += o;
            ss[r] += o * o;
        }
    }
    #pragma unroll
    for (int off = 8; off >= 1; off >>= 1) {
        #pragma unroll
        for (int r = 0; r < 4; ++r) {
            s[r]  += __shfl_xor(s[r],  off);
            ss[r] += __shfl_xor(ss[r], off);
        }
    }
    float mu[4], rstd[4];
    #pragma unroll
    for (int r = 0; r < 4; ++r) {
        mu[r] = s[r] * (1.f / 128.f);
        float var = ss[r] * (1.f / 128.f) - mu[r] * mu[r];
        rstd[r] = rsqrtf(var + 1e-5f);
    }
    #pragma unroll
    for (int nt = 0; nt < 8; ++nt) {
        int col = nt * 16 + arow;
        float gm = gamma[col], bt = beta[col];
        #pragma unroll
        for (int r = 0; r < 4; ++r) {
            int node = n0 + g4 * 4 + r;
            if (node < N)
                out[(size_t)node * 128 + col] = (u2[nt][r] - mu[r]) * rstd[r] * gm + bt;
        }
    }
}

extern "C" void kernel_launch(void* const* d_in, const int* in_sizes, int n_in,
                              void* d_out, int out_size, void* d_ws, size_t ws_size,
                              hipStream_t stream)
{
    const float* x    = (const float*)d_in[0];
    const int*   ei   = (const int*)  d_in[1];
    const float* ea   = (const float*)d_in[2];
    const float* Wm1  = (const float*)d_in[3];
    const float* bm1  = (const float*)d_in[4];
    const float* Wm2  = (const float*)d_in[5];
    const float* bm2  = (const float*)d_in[6];
    const float* Wg   = (const float*)d_in[7];
    const float* bg   = (const float*)d_in[8];
    const float* Wu1  = (const float*)d_in[9];
    const float* bu1  = (const float*)d_in[10];
    const float* Wu2  = (const float*)d_in[11];
    const float* bu2  = (const float*)d_in[12];
    const float* gmma = (const float*)d_in[13];
    const float* beta = (const float*)d_in[14];
    float* out = (float*)d_out;

    const int N = in_sizes[0] / HID;
    const int E = in_sizes[1] / 2;

    // workspace carve-up
    unsigned short* S1b  = (unsigned short*)d_ws;            // N*128 bf16
    unsigned short* Tb   = S1b + (size_t)N * HID;            // N*128 bf16
    float*          HS   = (float*)(Tb + (size_t)N * HID);   // N*128 f32
    unsigned short* W1f  = (unsigned short*)(HS + (size_t)N * HID); // 32768
    unsigned short* WgH  = W1f + 32768;
    unsigned short* WgL  = WgH + 32768;
    unsigned short* Wu1H = WgL + 32768;
    unsigned short* Wu1L = Wu1H + 32768;
    unsigned short* Wu2H = Wu1L + 32768;
    unsigned short* Wu2L = Wu2H + 16384;
    float*          bcg  = (float*)(Wu2L + 16384);           // 128
    float*          bcu  = bcg + 128;                        // 128
    float*          Cbuf = bcu + 128;                        // 16384 f32
    float*          Stk  = Cbuf + 16384;                     // 32768 f32
    unsigned*       cnt  = (unsigned*)(Stk + 32768);         // N
    unsigned*       cur  = cnt + N;                          // N
    int*            srcS = (int*)(cur + N);                  // E
    float*          eaS  = (float*)(srcS + E);               // 3E
    size_t need_sort = (size_t)((char*)(eaS + (size_t)E * 3) - (char*)d_ws);
    size_t need_min  = (size_t)((char*)(cur + N) - (char*)d_ws);
    const bool tierA = (ws_size >= need_sort);
    (void)need_min;

    // weights prep
    prep_w<<<dim3(16), dim3(256), 0, stream>>>(Wm1, W1f, 8);
    compose_k<<<dim3(64), dim3(256), 0, stream>>>(Wm2, Wg + 128 * 128, Cbuf);
    bias_comp_k<<<dim3(1), dim3(128), 0, stream>>>(bm2, Wg + 128 * 128, bcg);
    stack_k<<<dim3(128), dim3(256), 0, stream>>>(Wg, Cbuf, Stk);
    prep_w_split<<<dim3(16), dim3(256), 0, stream>>>(Stk, WgH, WgL, 8);
    compose_k<<<dim3(64), dim3(256), 0, stream>>>(Wm2, Wu1 + 128 * 128, Cbuf);
    bias_comp_k<<<dim3(1), dim3(128), 0, stream>>>(bm2, Wu1 + 128 * 128, bcu);
    stack_k<<<dim3(128), dim3(256), 0, stream>>>(Wu1, Cbuf, Stk);
    prep_w_split<<<dim3(16), dim3(256), 0, stream>>>(Stk, Wu1H, Wu1L, 8);
    prep_w_split<<<dim3(8), dim3(256), 0, stream>>>(Wu2, Wu2H, Wu2L, 4);

    // dense per-node S1/T
    s1t_gemm<<<dim3((N + 63) / 64), dim3(256), 0, stream>>>(x, W1f, S1b, Tb, N);

    // degree histogram (needed in both tiers)
    hipMemsetAsync(cnt, 0, (size_t)N * sizeof(unsigned), stream);
    hist_k<<<dim3((E + 255) / 256), dim3(256), 0, stream>>>(ei, cnt, E);

    if (tierA) {
        scan_k<<<dim3(1), dim3(1024), 0, stream>>>(cnt, cur, N);
        scatter_k<<<dim3((E + 255) / 256), dim3(256), 0, stream>>>(ei, ea, cur, srcS, eaS, E);
        csr_edge_k<<<dim3(512), dim3(256), 0, stream>>>(
            S1b, Tb, srcS, eaS, cnt, cur, Wm1 + 256 * HID, bm1, HS, N);
    } else {
        hipMemsetAsync(HS, 0, (size_t)N * HID * sizeof(float), stream);
        atomic_edge_k<<<dim3(1024), dim3(256), 0, stream>>>(
            S1b, Tb, ei, ea, Wm1 + 256 * HID, bm1, HS, E);
    }

    int ntilesN = (N + 15) / 16;
    node_mfma<<<dim3((ntilesN + 3) / 4), dim3(256), 0, stream>>>(
        x, HS, cnt, bcg, bcu,
        WgH, WgL, Wu1H, Wu1L, Wu2H, Wu2L,
        bg, bu1, bu2, gmma, beta, out, N);
}

// Round 12
// 384.463 us; speedup vs baseline: 1.3442x; 1.3442x over previous
//
#include <hip/hip_runtime.h>
#include <hip/hip_bf16.h>

#define HID 128

typedef __attribute__((ext_vector_type(8))) short short8;
typedef __attribute__((ext_vector_type(4))) float f32x4;

__device__ __forceinline__ unsigned short f2bf(float f) {
    unsigned int u = __builtin_bit_cast(unsigned int, f);
    u += 0x7FFFu + ((u >> 16) & 1u);
    return (unsigned short)(u >> 16);
}
__device__ __forceinline__ float bf2f(unsigned short h) {
    unsigned int u = ((unsigned int)h) << 16;
    return __builtin_bit_cast(float, u);
}

// ---------------- prep: W[k][128] f32 -> fragment order Wf[ks][nt][lane][j] bf16 ----------------
__global__ void prep_w(const float* __restrict__ W, unsigned short* __restrict__ Wf, int nks) {
    int t = blockIdx.x * 256 + threadIdx.x;
    if (t >= nks * 8 * 64) return;
    int lane = t & 63, nt = (t >> 6) & 7, ks = t >> 9;
    int kb  = ks * 32 + ((lane >> 4) << 3);
    int col = (nt << 4) + (lane & 15);
    union { unsigned short u[8]; uint4 q; } p;
    #pragma unroll
    for (int j = 0; j < 8; ++j) p.u[j] = f2bf(W[(size_t)(kb + j) * 128 + col]);
    *(uint4*)(Wf + (size_t)t * 8) = p.q;
}

// hi/lo split fragments for near-fp32 node GEMMs
__global__ void prep_w_split(const float* __restrict__ W,
                             unsigned short* __restrict__ Wh,
                             unsigned short* __restrict__ Wl, int nks) {
    int t = blockIdx.x * 256 + threadIdx.x;
    if (t >= nks * 8 * 64) return;
    int lane = t & 63, nt = (t >> 6) & 7, ks = t >> 9;
    int kb  = ks * 32 + ((lane >> 4) << 3);
    int col = (nt << 4) + (lane & 15);
    union { unsigned short u[8]; uint4 q; } ph, pl;
    #pragma unroll
    for (int j = 0; j < 8; ++j) {
        float w = W[(size_t)(kb + j) * 128 + col];
        unsigned short h = f2bf(w);
        ph.u[j] = h;
        pl.u[j] = f2bf(w - bf2f(h));
    }
    *(uint4*)(Wh + (size_t)t * 8) = ph.q;
    *(uint4*)(Wl + (size_t)t * 8) = pl.q;
}

// ---------------- composed weights: C = Wm2 @ Bpart ----------------
__global__ void compose_k(const float* __restrict__ A, const float* __restrict__ B,
                          float* __restrict__ C) {
    int t = blockIdx.x * 256 + threadIdx.x;
    if (t >= 128 * 128) return;
    int i = t >> 7, j = t & 127;
    float s = 0.f;
    for (int k = 0; k < 128; ++k) s = fmaf(A[i * 128 + k], B[(size_t)k * 128 + j], s);
    C[t] = s;
}
__global__ void bias_comp_k(const float* __restrict__ b2, const float* __restrict__ B,
                            float* __restrict__ bc) {
    int j = threadIdx.x;
    if (j >= 128) return;
    float s = 0.f;
    for (int k = 0; k < 128; ++k) s = fmaf(b2[k], B[(size_t)k * 128 + j], s);
    bc[j] = s;
}
__global__ void stack_k(const float* __restrict__ Wtop, const float* __restrict__ C,
                        float* __restrict__ S) {
    int t = blockIdx.x * 256 + threadIdx.x;
    if (t >= 256 * 128) return;
    int r = t >> 7, c = t & 127;
    S[t] = (r < 128) ? Wtop[(size_t)r * 128 + c] : C[(size_t)(r - 128) * 128 + c];
}

// ---------------- counting sort by dst -> fused 16B edge records ----------------
__global__ void hist_k(const int* __restrict__ ei, unsigned* __restrict__ cnt, int E) {
    int e = blockIdx.x * 256 + threadIdx.x;
    if (e < E) atomicAdd(&cnt[ei[E + e]], 1u);
}

__global__ void scan_k(const unsigned* __restrict__ cnt, unsigned* __restrict__ cur, int n) {
    __shared__ unsigned wsum[16];
    int tid = threadIdx.x, lane = tid & 63, w = tid >> 6;
    unsigned carry = 0;
    for (int base = 0; base < n; base += 1024) {
        int i = base + tid;
        unsigned v = (i < n) ? cnt[i] : 0u;
        unsigned s = v;
        #pragma unroll
        for (int off = 1; off < 64; off <<= 1) {
            unsigned t = __shfl_up(s, off);
            if (lane >= off) s += t;
        }
        if (lane == 63) wsum[w] = s;
        __syncthreads();
        if (tid < 16) {
            unsigned t = wsum[tid];
            #pragma unroll
            for (int off = 1; off < 16; off <<= 1) {
                unsigned u = __shfl_up(t, off);
                if (tid >= off) t += u;
            }
            wsum[tid] = t;
        }
        __syncthreads();
        unsigned woff = (w == 0) ? 0u : wsum[w - 1];
        if (i < n) cur[i] = carry + woff + s - v;
        unsigned tot = wsum[15];
        __syncthreads();
        carry += tot;
    }
}

__global__ void scatter_k(const int* __restrict__ ei, const float* __restrict__ ea,
                          unsigned* __restrict__ cur, uint4* __restrict__ rec, int E) {
    int e = blockIdx.x * 256 + threadIdx.x;
    if (e >= E) return;
    int d = ei[E + e];
    unsigned pos = atomicAdd(&cur[d], 1u);
    uint4 r;
    r.x = (unsigned)ei[e];
    r.y = __builtin_bit_cast(unsigned, ea[(size_t)e * 3 + 0]);
    r.z = __builtin_bit_cast(unsigned, ea[(size_t)e * 3 + 1]);
    r.w = __builtin_bit_cast(unsigned, ea[(size_t)e * 3 + 2]);
    rec[pos] = r;
}

// ---------------- S1 = x@W1[:128], T = x@W1[128:256], B from LDS ----------------
__global__ __launch_bounds__(256, 2)
void s1t_gemm(const float* __restrict__ x, const unsigned short* __restrict__ W1f,
              unsigned short* __restrict__ S1b, unsigned short* __restrict__ Tb, int N)
{
    __shared__ alignas(16) unsigned short sW[32768];   // 64 KB: full W1f
    const int tid  = threadIdx.x;
    for (int i = tid; i < 4096; i += 256)
        ((uint4*)sW)[i] = ((const uint4*)W1f)[i];
    __syncthreads();

    const int lane = tid & 63;
    const int wid  = tid >> 6;
    const int n0   = (blockIdx.x * 4 + wid) * 16;
    if (n0 >= N) return;
    const int arow = lane & 15;
    const int g4   = lane >> 4;

    int nr = n0 + arow; if (nr >= N) nr = N - 1;
    const float* px = x + (size_t)nr * 128 + g4 * 8;

    short8 af[4];
    #pragma unroll
    for (int ks = 0; ks < 4; ++ks) {
        float4 v0 = *(const float4*)(px + ks * 32);
        float4 v1 = *(const float4*)(px + ks * 32 + 4);
        float v[8] = { v0.x, v0.y, v0.z, v0.w, v1.x, v1.y, v1.z, v1.w };
        #pragma unroll
        for (int j = 0; j < 8; ++j) af[ks][j] = (short)f2bf(v[j]);
    }

    f32x4 s1[8], tt[8];
    #pragma unroll
    for (int i = 0; i < 8; ++i) { s1[i] = (f32x4)0.f; tt[i] = (f32x4)0.f; }
    #pragma unroll
    for (int ks = 0; ks < 4; ++ks) {
        #pragma unroll
        for (int nt = 0; nt < 8; ++nt) {
            short8 b1 = *(const short8*)(sW + (size_t)((ks * 8 + nt) * 64 + lane) * 8);
            short8 b2 = *(const short8*)(sW + (size_t)(((ks + 4) * 8 + nt) * 64 + lane) * 8);
            s1[nt] = __builtin_amdgcn_mfma_f32_16x16x32_bf16(af[ks], b1, s1[nt], 0, 0, 0);
            tt[nt] = __builtin_amdgcn_mfma_f32_16x16x32_bf16(af[ks], b2, tt[nt], 0, 0, 0);
        }
    }
    #pragma unroll
    for (int nt = 0; nt < 8; ++nt) {
        int col = nt * 16 + arow;
        #pragma unroll
        for (int r = 0; r < 4; ++r) {
            int node = n0 + g4 * 4 + r;
            if (node < N) {
                S1b[(size_t)node * 128 + col] = f2bf(s1[nt][r]);
                Tb [(size_t)node * 128 + col] = f2bf(tt[nt][r]);
            }
        }
    }
}

// ---------------- CSR edge kernel: HS[d] = sum relu(S1[src]+T[d]+ea.W1tail+b1) ----------------
// One wave per dst; fused 16B records; depth-1 pipeline; zero atomics.
__global__ __launch_bounds__(256, 8)
void csr_edge_k(const unsigned short* __restrict__ S1b, const unsigned short* __restrict__ Tb,
                const uint4* __restrict__ rec,
                const unsigned* __restrict__ cnt, const unsigned* __restrict__ cur,
                const float* __restrict__ W1tail, const float* __restrict__ bm1,
                float* __restrict__ HS, int N)
{
    const int lane = threadIdx.x & 63;
    const int wid  = threadIdx.x >> 6;
    const int gw   = blockIdx.x * 4 + wid;
    const int stride = gridDim.x * 4;
    const int c2 = lane * 2;

    const float w00 = W1tail[c2],       w01 = W1tail[c2 + 1];
    const float w10 = W1tail[128 + c2], w11 = W1tail[128 + c2 + 1];
    const float w20 = W1tail[256 + c2], w21 = W1tail[256 + c2 + 1];
    const float b0  = bm1[c2],          b1v = bm1[c2 + 1];

    for (int d = gw; d < N; d += stride) {
        int e1 = (int)cur[d];
        int c  = (int)cnt[d];
        int e0 = e1 - c;
        unsigned tv = *(const unsigned*)(Tb + (size_t)d * 128 + c2);
        float t0 = bf2f((unsigned short)(tv & 0xffff)) + b0;
        float t1 = bf2f((unsigned short)(tv >> 16))    + b1v;
        float a0 = 0.f, a1 = 0.f;
        if (c > 0) {
            uint4 r = rec[e0];
            for (int e = e0; e < e1; ++e) {
                uint4 rn = {0, 0, 0, 0};
                if (e + 1 < e1) rn = rec[e + 1];                         // prefetch next record
                unsigned sv = *(const unsigned*)(S1b + (size_t)r.x * 128 + c2); // current S1 row
                float x0 = __builtin_bit_cast(float, r.y);
                float x1 = __builtin_bit_cast(float, r.z);
                float x2 = __builtin_bit_cast(float, r.w);
                float h0 = bf2f((unsigned short)(sv & 0xffff)) + t0;
                float h1 = bf2f((unsigned short)(sv >> 16))    + t1;
                h0 = fmaf(x0, w00, h0); h0 = fmaf(x1, w10, h0); h0 = fmaf(x2, w20, h0);
                h1 = fmaf(x0, w01, h1); h1 = fmaf(x1, w11, h1); h1 = fmaf(x2, w21, h1);
                a0 += fmaxf(h0, 0.f);
                a1 += fmaxf(h1, 0.f);
                r = rn;
            }
        }
        float2 o; o.x = a0; o.y = a1;
        *(float2*)(HS + (size_t)d * 128 + c2) = o;
    }
}

// tier-B fallback: per-edge atomics from raw inputs (HS pre-zeroed)
__global__ __launch_bounds__(256, 8)
void atomic_edge_k(const unsigned short* __restrict__ S1b, const unsigned short* __restrict__ Tb,
                   const int* __restrict__ ei, const float* __restrict__ ea,
                   const float* __restrict__ W1tail, const float* __restrict__ bm1,
                   float* __restrict__ HS, int E)
{
    const int lane = threadIdx.x & 63;
    const int wid  = threadIdx.x >> 6;
    const int gw   = blockIdx.x * 4 + wid;
    const int stride = gridDim.x * 4;
    const int c2 = lane * 2;

    const float w00 = W1tail[c2],       w01 = W1tail[c2 + 1];
    const float w10 = W1tail[128 + c2], w11 = W1tail[128 + c2 + 1];
    const float w20 = W1tail[256 + c2], w21 = W1tail[256 + c2 + 1];
    const float b0  = bm1[c2],          b1v = bm1[c2 + 1];

    for (int e = gw; e < E; e += stride) {
        int s = ei[e], d = ei[E + e];
        float x0 = ea[(size_t)e * 3 + 0];
        float x1 = ea[(size_t)e * 3 + 1];
        float x2 = ea[(size_t)e * 3 + 2];
        unsigned tv = *(const unsigned*)(Tb + (size_t)d * 128 + c2);
        unsigned sv = *(const unsigned*)(S1b + (size_t)s * 128 + c2);
        float h0 = bf2f((unsigned short)(sv & 0xffff)) + bf2f((unsigned short)(tv & 0xffff)) + b0;
        float h1 = bf2f((unsigned short)(sv >> 16))    + bf2f((unsigned short)(tv >> 16))    + b1v;
        h0 = fmaf(x0, w00, h0); h0 = fmaf(x1, w10, h0); h0 = fmaf(x2, w20, h0);
        h1 = fmaf(x0, w01, h1); h1 = fmaf(x1, w11, h1); h1 = fmaf(x2, w21, h1);
        unsafeAtomicAdd(HS + (size_t)d * 128 + c2,     fmaxf(h0, 0.f));
        unsafeAtomicAdd(HS + (size_t)d * 128 + c2 + 1, fmaxf(h1, 0.f));
    }
}

// ---------------- Node kernel: [x|HS] @ stacked-composed weights + deg bias + LN ----------------
__global__ __launch_bounds__(256, 3)
void node_mfma(const float* __restrict__ x,
               const float* __restrict__ HS,
               const unsigned* __restrict__ cnt,
               const float* __restrict__ bcg, const float* __restrict__ bcu,
               const unsigned short* __restrict__ WgH, const unsigned short* __restrict__ WgL,
               const unsigned short* __restrict__ Wu1H, const unsigned short* __restrict__ Wu1L,
               const unsigned short* __restrict__ Wu2H, const unsigned short* __restrict__ Wu2L,
               const float* __restrict__ bg, const float* __restrict__ bu1,
               const float* __restrict__ bu2,
               const float* __restrict__ gamma, const float* __restrict__ beta,
               float* __restrict__ out, int N)
{
    __shared__ alignas(16) char Hs[4][8192];

    const int tid  = threadIdx.x;
    const int lane = tid & 63;
    const int wid  = tid >> 6;
    const int n0   = (blockIdx.x * 4 + wid) * 16;
    if (n0 >= N) return;

    const int arow = lane & 15;
    const int g4   = lane >> 4;

    int nr = n0 + arow; if (nr >= N) nr = N - 1;
    const float* px = x  + (size_t)nr * 128 + g4 * 8;
    const float* pa = HS + (size_t)nr * 128 + g4 * 8;

    short8 ah[8], al[8];
    #pragma unroll
    for (int ks = 0; ks < 8; ++ks) {
        const float* p = (ks < 4) ? (px + ks * 32) : (pa + (ks - 4) * 32);
        float4 v0 = *(const float4*)p;
        float4 v1 = *(const float4*)(p + 4);
        float v[8] = { v0.x, v0.y, v0.z, v0.w, v1.x, v1.y, v1.z, v1.w };
        #pragma unroll
        for (int j = 0; j < 8; ++j) {
            unsigned short h = f2bf(v[j]);
            ah[ks][j] = (short)h;
            al[ks][j] = (short)f2bf(v[j] - bf2f(h));
        }
    }

    float degf[4];
    #pragma unroll
    for (int r = 0; r < 4; ++r) {
        int node = n0 + g4 * 4 + r;
        degf[r] = (node < N) ? (float)cnt[node] : 0.f;
    }

    f32x4 ga[8];
    #pragma unroll
    for (int i = 0; i < 8; ++i) ga[i] = (f32x4)0.f;
    #pragma unroll
    for (int ks = 0; ks < 8; ++ks) {
        #pragma unroll
        for (int nt = 0; nt < 8; ++nt) {
            size_t o = (size_t)((ks * 8 + nt) * 64 + lane) * 8;
            short8 bh = *(const short8*)(WgH + o);
            short8 bl = *(const short8*)(WgL + o);
            ga[nt] = __builtin_amdgcn_mfma_f32_16x16x32_bf16(ah[ks], bh, ga[nt], 0, 0, 0);
            ga[nt] = __builtin_amdgcn_mfma_f32_16x16x32_bf16(al[ks], bh, ga[nt], 0, 0, 0);
            ga[nt] = __builtin_amdgcn_mfma_f32_16x16x32_bf16(ah[ks], bl, ga[nt], 0, 0, 0);
        }
    }

    f32x4 ua[8];
    #pragma unroll
    for (int i = 0; i < 8; ++i) ua[i] = (f32x4)0.f;
    #pragma unroll
    for (int ks = 0; ks < 8; ++ks) {
        #pragma unroll
        for (int nt = 0; nt < 8; ++nt) {
            size_t o = (size_t)((ks * 8 + nt) * 64 + lane) * 8;
            short8 bh = *(const short8*)(Wu1H + o);
            short8 bl = *(const short8*)(Wu1L + o);
            ua[nt] = __builtin_amdgcn_mfma_f32_16x16x32_bf16(ah[ks], bh, ua[nt], 0, 0, 0);
            ua[nt] = __builtin_amdgcn_mfma_f32_16x16x32_bf16(al[ks], bh, ua[nt], 0, 0, 0);
            ua[nt] = __builtin_amdgcn_mfma_f32_16x16x32_bf16(ah[ks], bl, ua[nt], 0, 0, 0);
        }
    }

    #pragma unroll
    for (int nt = 0; nt < 8; ++nt) {
        int col = nt * 16 + arow;
        float bgc = bcg[col], buc = bcu[col];
        #pragma unroll
        for (int r = 0; r < 4; ++r) {
            ga[nt][r] = fmaf(degf[r], bgc, ga[nt][r]);
            ua[nt][r] = fmaf(degf[r], buc, ua[nt][r]);
        }
    }

    #pragma unroll
    for (int nt = 0; nt < 8; ++nt) {
        int col = nt * 16 + arow;
        float b1 = bu1[col];
        #pragma unroll
        for (int r = 0; r < 4; ++r) {
            int row = g4 * 4 + r;
            float u = fmaxf(ua[nt][r] + b1, 0.f);
            unsigned short h = f2bf(u);
            unsigned short l = f2bf(u - bf2f(h));
            unsigned int pk = (unsigned int)h | ((unsigned int)l << 16);
            *(unsigned int*)(&Hs[wid][row * 512 + ((col * 4) ^ ((row & 15) << 4))]) = pk;
        }
    }

    #pragma unroll
    for (int nt = 0; nt < 8; ++nt) {
        int col = nt * 16 + arow;
        float b = bg[col];
        #pragma unroll
        for (int r = 0; r < 4; ++r)
            ga[nt][r] = 1.f / (1.f + expf(-(ga[nt][r] + b)));
    }
    __syncthreads();

    f32x4 u2[8];
    #pragma unroll
    for (int i = 0; i < 8; ++i) u2[i] = (f32x4)0.f;
    #pragma unroll
    for (int ks = 0; ks < 4; ++ks) {
        int b0 = ks * 128 + g4 * 32;
        unsigned int q0[4], q1[4];
        *(uint4*)q0 = *(const uint4*)(&Hs[wid][arow * 512 + ( b0       ^ (arow << 4))]);
        *(uint4*)q1 = *(const uint4*)(&Hs[wid][arow * 512 + ((b0 + 16) ^ (arow << 4))]);
        short8 a2h, a2l;
        #pragma unroll
        for (int j = 0; j < 4; ++j) {
            a2h[j]     = (short)(q0[j] & 0xffff);
            a2l[j]     = (short)(q0[j] >> 16);
            a2h[4 + j] = (short)(q1[j] & 0xffff);
            a2l[4 + j] = (short)(q1[j] >> 16);
        }
        #pragma unroll
        for (int nt = 0; nt < 8; ++nt) {
            size_t o = (size_t)((ks * 8 + nt) * 64 + lane) * 8;
            short8 bh = *(const short8*)(Wu2H + o);
            short8 bl = *(const short8*)(Wu2L + o);
            u2[nt] = __builtin_amdgcn_mfma_f32_16x16x32_bf16(a2h, bh, u2[nt], 0, 0, 0);
            u2[nt] = __builtin_amdgcn_mfma_f32_16x16x32_bf16(a2l, bh, u2[nt], 0, 0, 0);
            u2[nt] = __builtin_amdgcn_mfma_f32_16x16x32_bf16(a2h, bl, u2[nt], 0, 0, 0);
        }
    }

    float s[4]  = {0.f, 0.f, 0.f, 0.f};
    float ss[4] = {0.f, 0.f, 0.f, 0.f};
    #pragma unroll
    for (int nt = 0; nt < 8; ++nt) {
        int col = nt * 16 + arow;
        float b2 = bu2[col];
        #pragma unroll
        for (int r = 0; r < 4; ++r) {
            int node = n0 + g4 * 4 + r;
            float xv = x[(size_t)node * 128 + col];
            float g  = ga[nt][r];
            float o  = g * (u2[nt][r] + b2) + (1.f - g) * xv;
            u2[nt][r] = o;
            s[r]  += o;
            ss[r] += o * o;
        }
    }
    #pragma unroll
    for (int off = 8; off >= 1; off >>= 1) {
        #pragma unroll
        for (int r = 0; r < 4; ++r) {
            s[r]  += __shfl_xor(s[r],  off);
            ss[r] += __shfl_xor(ss[r], off);
        }
    }
    float mu[4], rstd[4];
    #pragma unroll
    for (int r = 0; r < 4; ++r) {
        mu[r] = s[r] * (1.f / 128.f);
        float var = ss[r] * (1.f / 128.f) - mu[r] * mu[r];
        rstd[r] = rsqrtf(var + 1e-5f);
    }
    #pragma unroll
    for (int nt = 0; nt < 8; ++nt) {
        int col = nt * 16 + arow;
        float gm = gamma[col], bt = beta[col];
        #pragma unroll
        for (int r = 0; r < 4; ++r) {
            int node = n0 + g4 * 4 + r;
            if (node < N)
                out[(size_t)node * 128 + col] = (u2[nt][r] - mu[r]) * rstd[r] * gm + bt;
        }
    }
}

extern "C" void kernel_launch(void* const* d_in, const int* in_sizes, int n_in,
                              void* d_out, int out_size, void* d_ws, size_t ws_size,
                              hipStream_t stream)
{
    const float* x    = (const float*)d_in[0];
    const int*   ei   = (const int*)  d_in[1];
    const float* ea   = (const float*)d_in[2];
    const float* Wm1  = (const float*)d_in[3];
    const float* bm1  = (const float*)d_in[4];
    const float* Wm2  = (const float*)d_in[5];
    const float* bm2  = (const float*)d_in[6];
    const float* Wg   = (const float*)d_in[7];
    const float* bg   = (const float*)d_in[8];
    const float* Wu1  = (const float*)d_in[9];
    const float* bu1  = (const float*)d_in[10];
    const float* Wu2  = (const float*)d_in[11];
    const float* bu2  = (const float*)d_in[12];
    const float* gmma = (const float*)d_in[13];
    const float* beta = (const float*)d_in[14];
    float* out = (float*)d_out;

    const int N = in_sizes[0] / HID;
    const int E = in_sizes[1] / 2;

    // workspace carve-up
    unsigned short* S1b  = (unsigned short*)d_ws;            // N*128 bf16
    unsigned short* Tb   = S1b + (size_t)N * HID;            // N*128 bf16
    float*          HS   = (float*)(Tb + (size_t)N * HID);   // N*128 f32
    unsigned short* W1f  = (unsigned short*)(HS + (size_t)N * HID); // 32768
    unsigned short* WgH  = W1f + 32768;
    unsigned short* WgL  = WgH + 32768;
    unsigned short* Wu1H = WgL + 32768;
    unsigned short* Wu1L = Wu1H + 32768;
    unsigned short* Wu2H = Wu1L + 32768;
    unsigned short* Wu2L = Wu2H + 16384;
    float*          bcg  = (float*)(Wu2L + 16384);           // 128
    float*          bcu  = bcg + 128;                        // 128
    float*          Cbuf = bcu + 128;                        // 16384 f32
    float*          Stk  = Cbuf + 16384;                     // 32768 f32
    unsigned*       cnt  = (unsigned*)(Stk + 32768);         // N
    unsigned*       cur  = cnt + N;                          // N
    uint4*          rec  = (uint4*)(cur + N);                // E x 16B (align: cur+N is 16B-aligned iff N%4==0; pad)
    rec = (uint4*)(((size_t)rec + 15) & ~(size_t)15);
    size_t need_sort = (size_t)((char*)(rec + E) - (char*)d_ws);
    const bool tierA = (ws_size >= need_sort);

    // weights prep
    prep_w<<<dim3(16), dim3(256), 0, stream>>>(Wm1, W1f, 8);
    compose_k<<<dim3(64), dim3(256), 0, stream>>>(Wm2, Wg + 128 * 128, Cbuf);
    bias_comp_k<<<dim3(1), dim3(128), 0, stream>>>(bm2, Wg + 128 * 128, bcg);
    stack_k<<<dim3(128), dim3(256), 0, stream>>>(Wg, Cbuf, Stk);
    prep_w_split<<<dim3(16), dim3(256), 0, stream>>>(Stk, WgH, WgL, 8);
    compose_k<<<dim3(64), dim3(256), 0, stream>>>(Wm2, Wu1 + 128 * 128, Cbuf);
    bias_comp_k<<<dim3(1), dim3(128), 0, stream>>>(bm2, Wu1 + 128 * 128, bcu);
    stack_k<<<dim3(128), dim3(256), 0, stream>>>(Wu1, Cbuf, Stk);
    prep_w_split<<<dim3(16), dim3(256), 0, stream>>>(Stk, Wu1H, Wu1L, 8);
    prep_w_split<<<dim3(8), dim3(256), 0, stream>>>(Wu2, Wu2H, Wu2L, 4);

    // dense per-node S1/T
    s1t_gemm<<<dim3((N + 63) / 64), dim3(256), 0, stream>>>(x, W1f, S1b, Tb, N);

    // degree histogram
    hipMemsetAsync(cnt, 0, (size_t)N * sizeof(unsigned), stream);
    hist_k<<<dim3((E + 255) / 256), dim3(256), 0, stream>>>(ei, cnt, E);

    if (tierA) {
        scan_k<<<dim3(1), dim3(1024), 0, stream>>>(cnt, cur, N);
        scatter_k<<<dim3((E + 255) / 256), dim3(256), 0, stream>>>(ei, ea, cur, rec, E);
        csr_edge_k<<<dim3(2048), dim3(256), 0, stream>>>(
            S1b, Tb, rec, cnt, cur, Wm1 + 256 * HID, bm1, HS, N);
    } else {
        hipMemsetAsync(HS, 0, (size_t)N * HID * sizeof(float), stream);
        atomic_edge_k<<<dim3(2048), dim3(256), 0, stream>>>(
            S1b, Tb, ei, ea, Wm1 + 256 * HID, bm1, HS, E);
    }

    int ntilesN = (N + 15) / 16;
    node_mfma<<<dim3((ntilesN + 3) / 4), dim3(256), 0, stream>>>(
        x, HS, cnt, bcg, bcu,
        WgH, WgL, Wu1H, Wu1L, Wu2H, Wu2L,
        bg, bu1, bu2, gmma, beta, out, N);
}

// Round 13
// 280.759 us; speedup vs baseline: 1.8407x; 1.3694x over previous
//
#include <hip/hip_runtime.h>
#include <hip/hip_bf16.h>

#define HID 128

typedef __attribute__((ext_vector_type(8))) short short8;
typedef __attribute__((ext_vector_type(4))) float f32x4;

__device__ __forceinline__ unsigned short f2bf(float f) {
    unsigned int u = __builtin_bit_cast(unsigned int, f);
    u += 0x7FFFu + ((u >> 16) & 1u);
    return (unsigned short)(u >> 16);
}
__device__ __forceinline__ float bf2f(unsigned short h) {
    unsigned int u = ((unsigned int)h) << 16;
    return __builtin_bit_cast(float, u);
}

// ---------------- prep: W[k][128] f32 -> fragment order Wf[ks][nt][lane][j] bf16 ----------------
__global__ void prep_w(const float* __restrict__ W, unsigned short* __restrict__ Wf, int nks) {
    int t = blockIdx.x * 256 + threadIdx.x;
    if (t >= nks * 8 * 64) return;
    int lane = t & 63, nt = (t >> 6) & 7, ks = t >> 9;
    int kb  = ks * 32 + ((lane >> 4) << 3);
    int col = (nt << 4) + (lane & 15);
    union { unsigned short u[8]; uint4 q; } p;
    #pragma unroll
    for (int j = 0; j < 8; ++j) p.u[j] = f2bf(W[(size_t)(kb + j) * 128 + col]);
    *(uint4*)(Wf + (size_t)t * 8) = p.q;
}

// hi/lo split fragments for near-fp32 node GEMMs
__global__ void prep_w_split(const float* __restrict__ W,
                             unsigned short* __restrict__ Wh,
                             unsigned short* __restrict__ Wl, int nks) {
    int t = blockIdx.x * 256 + threadIdx.x;
    if (t >= nks * 8 * 64) return;
    int lane = t & 63, nt = (t >> 6) & 7, ks = t >> 9;
    int kb  = ks * 32 + ((lane >> 4) << 3);
    int col = (nt << 4) + (lane & 15);
    union { unsigned short u[8]; uint4 q; } ph, pl;
    #pragma unroll
    for (int j = 0; j < 8; ++j) {
        float w = W[(size_t)(kb + j) * 128 + col];
        unsigned short h = f2bf(w);
        ph.u[j] = h;
        pl.u[j] = f2bf(w - bf2f(h));
    }
    *(uint4*)(Wh + (size_t)t * 8) = ph.q;
    *(uint4*)(Wl + (size_t)t * 8) = pl.q;
}

// ---------------- composed weights: C = Wm2 @ Bpart ----------------
__global__ void compose_k(const float* __restrict__ A, const float* __restrict__ B,
                          float* __restrict__ C) {
    int t = blockIdx.x * 256 + threadIdx.x;
    if (t >= 128 * 128) return;
    int i = t >> 7, j = t & 127;
    float s = 0.f;
    for (int k = 0; k < 128; ++k) s = fmaf(A[i * 128 + k], B[(size_t)k * 128 + j], s);
    C[t] = s;
}
__global__ void bias_comp_k(const float* __restrict__ b2, const float* __restrict__ B,
                            float* __restrict__ bc) {
    int j = threadIdx.x;
    if (j >= 128) return;
    float s = 0.f;
    for (int k = 0; k < 128; ++k) s = fmaf(b2[k], B[(size_t)k * 128 + j], s);
    bc[j] = s;
}
__global__ void stack_k(const float* __restrict__ Wtop, const float* __restrict__ C,
                        float* __restrict__ S) {
    int t = blockIdx.x * 256 + threadIdx.x;
    if (t >= 256 * 128) return;
    int r = t >> 7, c = t & 127;
    S[t] = (r < 128) ? Wtop[(size_t)r * 128 + c] : C[(size_t)(r - 128) * 128 + c];
}

// ---------------- counting sort by dst -> fused 16B edge records ----------------
__global__ void hist_k(const int* __restrict__ ei, unsigned* __restrict__ cnt, int E) {
    int e = blockIdx.x * 256 + threadIdx.x;
    if (e < E) atomicAdd(&cnt[ei[E + e]], 1u);
}

__global__ void scan_k(const unsigned* __restrict__ cnt, unsigned* __restrict__ cur, int n) {
    __shared__ unsigned wsum[16];
    int tid = threadIdx.x, lane = tid & 63, w = tid >> 6;
    unsigned carry = 0;
    for (int base = 0; base < n; base += 1024) {
        int i = base + tid;
        unsigned v = (i < n) ? cnt[i] : 0u;
        unsigned s = v;
        #pragma unroll
        for (int off = 1; off < 64; off <<= 1) {
            unsigned t = __shfl_up(s, off);
            if (lane >= off) s += t;
        }
        if (lane == 63) wsum[w] = s;
        __syncthreads();
        if (tid < 16) {
            unsigned t = wsum[tid];
            #pragma unroll
            for (int off = 1; off < 16; off <<= 1) {
                unsigned u = __shfl_up(t, off);
                if (tid >= off) t += u;
            }
            wsum[tid] = t;
        }
        __syncthreads();
        unsigned woff = (w == 0) ? 0u : wsum[w - 1];
        if (i < n) cur[i] = carry + woff + s - v;
        unsigned tot = wsum[15];
        __syncthreads();
        carry += tot;
    }
}

__global__ void scatter_k(const int* __restrict__ ei, const float* __restrict__ ea,
                          unsigned* __restrict__ cur, uint4* __restrict__ rec, int E) {
    int e = blockIdx.x * 256 + threadIdx.x;
    if (e >= E) return;
    int d = ei[E + e];
    unsigned pos = atomicAdd(&cur[d], 1u);
    uint4 r;
    r.x = (unsigned)ei[e];
    r.y = __builtin_bit_cast(unsigned, ea[(size_t)e * 3 + 0]);
    r.z = __builtin_bit_cast(unsigned, ea[(size_t)e * 3 + 1]);
    r.w = __builtin_bit_cast(unsigned, ea[(size_t)e * 3 + 2]);
    rec[pos] = r;
}

// ---------------- S1 = x@W1[:128], T = x@W1[128:256], B from LDS ----------------
__global__ __launch_bounds__(256, 2)
void s1t_gemm(const float* __restrict__ x, const unsigned short* __restrict__ W1f,
              unsigned short* __restrict__ S1b, unsigned short* __restrict__ Tb, int N)
{
    __shared__ alignas(16) unsigned short sW[32768];   // 64 KB: full W1f
    const int tid  = threadIdx.x;
    for (int i = tid; i < 4096; i += 256)
        ((uint4*)sW)[i] = ((const uint4*)W1f)[i];
    __syncthreads();

    const int lane = tid & 63;
    const int wid  = tid >> 6;
    const int n0   = (blockIdx.x * 4 + wid) * 16;
    if (n0 >= N) return;   // safe: no further block-wide barriers below
    const int arow = lane & 15;
    const int g4   = lane >> 4;

    int nr = n0 + arow; if (nr >= N) nr = N - 1;
    const float* px = x + (size_t)nr * 128 + g4 * 8;

    short8 af[4];
    #pragma unroll
    for (int ks = 0; ks < 4; ++ks) {
        float4 v0 = *(const float4*)(px + ks * 32);
        float4 v1 = *(const float4*)(px + ks * 32 + 4);
        float v[8] = { v0.x, v0.y, v0.z, v0.w, v1.x, v1.y, v1.z, v1.w };
        #pragma unroll
        for (int j = 0; j < 8; ++j) af[ks][j] = (short)f2bf(v[j]);
    }

    f32x4 s1[8], tt[8];
    #pragma unroll
    for (int i = 0; i < 8; ++i) { s1[i] = (f32x4)0.f; tt[i] = (f32x4)0.f; }
    #pragma unroll
    for (int ks = 0; ks < 4; ++ks) {
        #pragma unroll
        for (int nt = 0; nt < 8; ++nt) {
            short8 b1 = *(const short8*)(sW + (size_t)((ks * 8 + nt) * 64 + lane) * 8);
            short8 b2 = *(const short8*)(sW + (size_t)(((ks + 4) * 8 + nt) * 64 + lane) * 8);
            s1[nt] = __builtin_amdgcn_mfma_f32_16x16x32_bf16(af[ks], b1, s1[nt], 0, 0, 0);
            tt[nt] = __builtin_amdgcn_mfma_f32_16x16x32_bf16(af[ks], b2, tt[nt], 0, 0, 0);
        }
    }
    #pragma unroll
    for (int nt = 0; nt < 8; ++nt) {
        int col = nt * 16 + arow;
        #pragma unroll
        for (int r = 0; r < 4; ++r) {
            int node = n0 + g4 * 4 + r;
            if (node < N) {
                S1b[(size_t)node * 128 + col] = f2bf(s1[nt][r]);
                Tb [(size_t)node * 128 + col] = f2bf(tt[nt][r]);
            }
        }
    }
}

// ---------------- CSR edge kernel: depth-2 pipelined gather-reduce, zero atomics ----------------
__global__ __launch_bounds__(256, 8)
void csr_edge_k(const unsigned short* __restrict__ S1b, const unsigned short* __restrict__ Tb,
                const uint4* __restrict__ rec,
                const unsigned* __restrict__ cnt, const unsigned* __restrict__ cur,
                const float* __restrict__ W1tail, const float* __restrict__ bm1,
                float* __restrict__ HS, int N)
{
    const int lane = threadIdx.x & 63;
    const int wid  = threadIdx.x >> 6;
    const int gw   = blockIdx.x * 4 + wid;
    const int stride = gridDim.x * 4;
    const int c2 = lane * 2;

    const float w00 = W1tail[c2],       w01 = W1tail[c2 + 1];
    const float w10 = W1tail[128 + c2], w11 = W1tail[128 + c2 + 1];
    const float w20 = W1tail[256 + c2], w21 = W1tail[256 + c2 + 1];
    const float b0  = bm1[c2],          b1v = bm1[c2 + 1];

    for (int d = gw; d < N; d += stride) {
        int e1 = (int)cur[d];
        int c  = (int)cnt[d];
        int e0 = e1 - c;
        unsigned tv = *(const unsigned*)(Tb + (size_t)d * 128 + c2);
        float t0 = bf2f((unsigned short)(tv & 0xffff)) + b0;
        float t1 = bf2f((unsigned short)(tv >> 16))    + b1v;
        float a0 = 0.f, a1 = 0.f;
        if (c > 0) {
            uint4 r0 = rec[e0];
            uint4 r1 = (c > 1) ? rec[e0 + 1] : make_uint4(0u, 0u, 0u, 0u);
            unsigned sv0 = *(const unsigned*)(S1b + (size_t)r0.x * 128 + c2);
            for (int e = e0; e < e1; ++e) {
                uint4 r2 = (e + 2 < e1) ? rec[e + 2] : make_uint4(0u, 0u, 0u, 0u);
                unsigned sv1 = (e + 1 < e1)
                    ? *(const unsigned*)(S1b + (size_t)r1.x * 128 + c2) : 0u;
                float x0 = __builtin_bit_cast(float, r0.y);
                float x1 = __builtin_bit_cast(float, r0.z);
                float x2 = __builtin_bit_cast(float, r0.w);
                float h0 = bf2f((unsigned short)(sv0 & 0xffff)) + t0;
                float h1 = bf2f((unsigned short)(sv0 >> 16))    + t1;
                h0 = fmaf(x0, w00, h0); h0 = fmaf(x1, w10, h0); h0 = fmaf(x2, w20, h0);
                h1 = fmaf(x0, w01, h1); h1 = fmaf(x1, w11, h1); h1 = fmaf(x2, w21, h1);
                a0 += fmaxf(h0, 0.f);
                a1 += fmaxf(h1, 0.f);
                r0 = r1; r1 = r2; sv0 = sv1;
            }
        }
        float2 o; o.x = a0; o.y = a1;
        *(float2*)(HS + (size_t)d * 128 + c2) = o;
    }
}

// tier-B fallback: per-edge atomics from raw inputs (HS pre-zeroed)
__global__ __launch_bounds__(256, 8)
void atomic_edge_k(const unsigned short* __restrict__ S1b, const unsigned short* __restrict__ Tb,
                   const int* __restrict__ ei, const float* __restrict__ ea,
                   const float* __restrict__ W1tail, const float* __restrict__ bm1,
                   float* __restrict__ HS, int E)
{
    const int lane = threadIdx.x & 63;
    const int wid  = threadIdx.x >> 6;
    const int gw   = blockIdx.x * 4 + wid;
    const int stride = gridDim.x * 4;
    const int c2 = lane * 2;

    const float w00 = W1tail[c2],       w01 = W1tail[c2 + 1];
    const float w10 = W1tail[128 + c2], w11 = W1tail[128 + c2 + 1];
    const float w20 = W1tail[256 + c2], w21 = W1tail[256 + c2 + 1];
    const float b0  = bm1[c2],          b1v = bm1[c2 + 1];

    for (int e = gw; e < E; e += stride) {
        int s = ei[e], d = ei[E + e];
        float x0 = ea[(size_t)e * 3 + 0];
        float x1 = ea[(size_t)e * 3 + 1];
        float x2 = ea[(size_t)e * 3 + 2];
        unsigned tv = *(const unsigned*)(Tb + (size_t)d * 128 + c2);
        unsigned sv = *(const unsigned*)(S1b + (size_t)s * 128 + c2);
        float h0 = bf2f((unsigned short)(sv & 0xffff)) + bf2f((unsigned short)(tv & 0xffff)) + b0;
        float h1 = bf2f((unsigned short)(sv >> 16))    + bf2f((unsigned short)(tv >> 16))    + b1v;
        h0 = fmaf(x0, w00, h0); h0 = fmaf(x1, w10, h0); h0 = fmaf(x2, w20, h0);
        h1 = fmaf(x0, w01, h1); h1 = fmaf(x1, w11, h1); h1 = fmaf(x2, w21, h1);
        unsafeAtomicAdd(HS + (size_t)d * 128 + c2,     fmaxf(h0, 0.f));
        unsafeAtomicAdd(HS + (size_t)d * 128 + c2 + 1, fmaxf(h1, 0.f));
    }
}

// ---------------- Node kernel: LDS-staged weights, ks-chunked ----------------
__global__ __launch_bounds__(256, 2)
void node_mfma(const float* __restrict__ x,
               const float* __restrict__ HS,
               const unsigned* __restrict__ cnt,
               const float* __restrict__ bcg, const float* __restrict__ bcu,
               const unsigned short* __restrict__ WgH, const unsigned short* __restrict__ WgL,
               const unsigned short* __restrict__ Wu1H, const unsigned short* __restrict__ Wu1L,
               const unsigned short* __restrict__ Wu2H, const unsigned short* __restrict__ Wu2L,
               const float* __restrict__ bg, const float* __restrict__ bu1,
               const float* __restrict__ bu2,
               const float* __restrict__ gamma, const float* __restrict__ beta,
               float* __restrict__ out, int N)
{
    __shared__ alignas(16) unsigned short sB[16384];   // 32 KB weight chunk
    __shared__ alignas(16) char Hs[4][8192];           // 32 KB u1 transpose

    const int tid  = threadIdx.x;
    const int lane = tid & 63;
    const int wid  = tid >> 6;
    const int n0   = (blockIdx.x * 4 + wid) * 16;
    // NO early return: all threads must reach block barriers (cooperative staging).

    const int arow = lane & 15;
    const int g4   = lane >> 4;

    int nr = n0 + arow; if (nr >= N) nr = N - 1;
    if (nr < 0) nr = 0;
    const float* px = x  + (size_t)nr * 128 + g4 * 8;
    const float* pa = HS + (size_t)nr * 128 + g4 * 8;

    short8 ah[8], al[8];
    #pragma unroll
    for (int ks = 0; ks < 8; ++ks) {
        const float* p = (ks < 4) ? (px + ks * 32) : (pa + (ks - 4) * 32);
        float4 v0 = *(const float4*)p;
        float4 v1 = *(const float4*)(p + 4);
        float v[8] = { v0.x, v0.y, v0.z, v0.w, v1.x, v1.y, v1.z, v1.w };
        #pragma unroll
        for (int j = 0; j < 8; ++j) {
            unsigned short h = f2bf(v[j]);
            ah[ks][j] = (short)h;
            al[ks][j] = (short)f2bf(v[j] - bf2f(h));
        }
    }

    float degf[4];
    #pragma unroll
    for (int r = 0; r < 4; ++r) {
        int node = n0 + g4 * 4 + r;
        degf[r] = (node >= 0 && node < N) ? (float)cnt[node] : 0.f;
    }

    // ---- gate + u1 GEMMs (K=256, 3-pass split), weights LDS-staged per ks ----
    f32x4 ga[8], ua[8];
    #pragma unroll
    for (int i = 0; i < 8; ++i) { ga[i] = (f32x4)0.f; ua[i] = (f32x4)0.f; }

    uint4* sB4 = (uint4*)sB;
    for (int ks = 0; ks < 8; ++ks) {
        #pragma unroll
        for (int i = 0; i < 2; ++i) {
            int idx = tid + i * 256;
            sB4[idx]        = ((const uint4*)WgH )[ks * 512 + idx];
            sB4[512 + idx]  = ((const uint4*)WgL )[ks * 512 + idx];
            sB4[1024 + idx] = ((const uint4*)Wu1H)[ks * 512 + idx];
            sB4[1536 + idx] = ((const uint4*)Wu1L)[ks * 512 + idx];
        }
        __syncthreads();
        #pragma unroll
        for (int nt = 0; nt < 8; ++nt) {
            size_t o = (size_t)(nt * 64 + lane) * 8;
            short8 bh = *(const short8*)(sB + o);
            short8 bl = *(const short8*)(sB + 4096 + o);
            ga[nt] = __builtin_amdgcn_mfma_f32_16x16x32_bf16(ah[ks], bh, ga[nt], 0, 0, 0);
            ga[nt] = __builtin_amdgcn_mfma_f32_16x16x32_bf16(al[ks], bh, ga[nt], 0, 0, 0);
            ga[nt] = __builtin_amdgcn_mfma_f32_16x16x32_bf16(ah[ks], bl, ga[nt], 0, 0, 0);
            short8 uh = *(const short8*)(sB + 8192 + o);
            short8 ul = *(const short8*)(sB + 12288 + o);
            ua[nt] = __builtin_amdgcn_mfma_f32_16x16x32_bf16(ah[ks], uh, ua[nt], 0, 0, 0);
            ua[nt] = __builtin_amdgcn_mfma_f32_16x16x32_bf16(al[ks], uh, ua[nt], 0, 0, 0);
            ua[nt] = __builtin_amdgcn_mfma_f32_16x16x32_bf16(ah[ks], ul, ua[nt], 0, 0, 0);
        }
        __syncthreads();
    }

    // + deg * composed-bias terms
    #pragma unroll
    for (int nt = 0; nt < 8; ++nt) {
        int col = nt * 16 + arow;
        float bgc = bcg[col], buc = bcu[col];
        #pragma unroll
        for (int r = 0; r < 4; ++r) {
            ga[nt][r] = fmaf(degf[r], bgc, ga[nt][r]);
            ua[nt][r] = fmaf(degf[r], buc, ua[nt][r]);
        }
    }

    // relu + bias, hi/lo pack into wave-private LDS (u1 transpose)
    #pragma unroll
    for (int nt = 0; nt < 8; ++nt) {
        int col = nt * 16 + arow;
        float b1 = bu1[col];
        #pragma unroll
        for (int r = 0; r < 4; ++r) {
            int row = g4 * 4 + r;
            float u = fmaxf(ua[nt][r] + b1, 0.f);
            unsigned short h = f2bf(u);
            unsigned short l = f2bf(u - bf2f(h));
            unsigned int pk = (unsigned int)h | ((unsigned int)l << 16);
            *(unsigned int*)(&Hs[wid][row * 512 + ((col * 4) ^ ((row & 15) << 4))]) = pk;
        }
    }

    // gate sigmoid
    #pragma unroll
    for (int nt = 0; nt < 8; ++nt) {
        int col = nt * 16 + arow;
        float b = bg[col];
        #pragma unroll
        for (int r = 0; r < 4; ++r)
            ga[nt][r] = 1.f / (1.f + expf(-(ga[nt][r] + b)));
    }
    __syncthreads();

    // ---- u2 GEMM (K=128, 3-pass), weights LDS-staged per ks ----
    f32x4 u2[8];
    #pragma unroll
    for (int i = 0; i < 8; ++i) u2[i] = (f32x4)0.f;
    for (int ks = 0; ks < 4; ++ks) {
        #pragma unroll
        for (int i = 0; i < 2; ++i) {
            int idx = tid + i * 256;
            sB4[idx]       = ((const uint4*)Wu2H)[ks * 512 + idx];
            sB4[512 + idx] = ((const uint4*)Wu2L)[ks * 512 + idx];
        }
        __syncthreads();
        int b0 = ks * 128 + g4 * 32;
        unsigned int q0[4], q1[4];
        *(uint4*)q0 = *(const uint4*)(&Hs[wid][arow * 512 + ( b0       ^ (arow << 4))]);
        *(uint4*)q1 = *(const uint4*)(&Hs[wid][arow * 512 + ((b0 + 16) ^ (arow << 4))]);
        short8 a2h, a2l;
        #pragma unroll
        for (int j = 0; j < 4; ++j) {
            a2h[j]     = (short)(q0[j] & 0xffff);
            a2l[j]     = (short)(q0[j] >> 16);
            a2h[4 + j] = (short)(q1[j] & 0xffff);
            a2l[4 + j] = (short)(q1[j] >> 16);
        }
        #pragma unroll
        for (int nt = 0; nt < 8; ++nt) {
            size_t o = (size_t)(nt * 64 + lane) * 8;
            short8 bh = *(const short8*)(sB + o);
            short8 bl = *(const short8*)(sB + 4096 + o);
            u2[nt] = __builtin_amdgcn_mfma_f32_16x16x32_bf16(a2h, bh, u2[nt], 0, 0, 0);
            u2[nt] = __builtin_amdgcn_mfma_f32_16x16x32_bf16(a2l, bh, u2[nt], 0, 0, 0);
            u2[nt] = __builtin_amdgcn_mfma_f32_16x16x32_bf16(a2h, bl, u2[nt], 0, 0, 0);
        }
        __syncthreads();
    }

    // ---- epilogue: gating + LayerNorm + store ----
    float s[4]  = {0.f, 0.f, 0.f, 0.f};
    float ss[4] = {0.f, 0.f, 0.f, 0.f};
    #pragma unroll
    for (int nt = 0; nt < 8; ++nt) {
        int col = nt * 16 + arow;
        float b2 = bu2[col];
        #pragma unroll
        for (int r = 0; r < 4; ++r) {
            int node = n0 + g4 * 4 + r;
            int nc = (node >= 0 && node < N) ? node : 0;
            float xv = x[(size_t)nc * 128 + col];
            float g  = ga[nt][r];
            float o  = g * (u2[nt][r] + b2) + (1.f - g) * xv;
            u2[nt][r] = o;
            s[r]  += o;
            ss[r] += o * o;
        }
    }
    #pragma unroll
    for (int off = 8; off >= 1; off >>= 1) {
        #pragma unroll
        for (int r = 0; r < 4; ++r) {
            s[r]  += __shfl_xor(s[r],  off);
            ss[r] += __shfl_xor(ss[r], off);
        }
    }
    float mu[4], rstd[4];
    #pragma unroll
    for (int r = 0; r < 4; ++r) {
        mu[r] = s[r] * (1.f / 128.f);
        float var = ss[r] * (1.f / 128.f) - mu[r] * mu[r];
        rstd[r] = rsqrtf(var + 1e-5f);
    }
    #pragma unroll
    for (int nt = 0; nt < 8; ++nt) {
        int col = nt * 16 + arow;
        float gm = gamma[col], bt = beta[col];
        #pragma unroll
        for (int r = 0; r < 4; ++r) {
            int node = n0 + g4 * 4 + r;
            if (node >= 0 && node < N)
                out[(size_t)node * 128 + col] = (u2[nt][r] - mu[r]) * rstd[r] * gm + bt;
        }
    }
}

extern "C" void kernel_launch(void* const* d_in, const int* in_sizes, int n_in,
                              void* d_out, int out_size, void* d_ws, size_t ws_size,
                              hipStream_t stream)
{
    const float* x    = (const float*)d_in[0];
    const int*   ei   = (const int*)  d_in[1];
    const float* ea   = (const float*)d_in[2];
    const float* Wm1  = (const float*)d_in[3];
    const float* bm1  = (const float*)d_in[4];
    const float* Wm2  = (const float*)d_in[5];
    const float* bm2  = (const float*)d_in[6];
    const float* Wg   = (const float*)d_in[7];
    const float* bg   = (const float*)d_in[8];
    const float* Wu1  = (const float*)d_in[9];
    const float* bu1  = (const float*)d_in[10];
    const float* Wu2  = (const float*)d_in[11];
    const float* bu2  = (const float*)d_in[12];
    const float* gmma = (const float*)d_in[13];
    const float* beta = (const float*)d_in[14];
    float* out = (float*)d_out;

    const int N = in_sizes[0] / HID;
    const int E = in_sizes[1] / 2;

    // workspace carve-up
    unsigned short* S1b  = (unsigned short*)d_ws;            // N*128 bf16
    unsigned short* Tb   = S1b + (size_t)N * HID;            // N*128 bf16
    float*          HS   = (float*)(Tb + (size_t)N * HID);   // N*128 f32
    unsigned short* W1f  = (unsigned short*)(HS + (size_t)N * HID); // 32768
    unsigned short* WgH  = W1f + 32768;
    unsigned short* WgL  = WgH + 32768;
    unsigned short* Wu1H = WgL + 32768;
    unsigned short* Wu1L = Wu1H + 32768;
    unsigned short* Wu2H = Wu1L + 32768;
    unsigned short* Wu2L = Wu2H + 16384;
    float*          bcg  = (float*)(Wu2L + 16384);           // 128
    float*          bcu  = bcg + 128;                        // 128
    float*          Cbuf = bcu + 128;                        // 16384 f32
    float*          Stk  = Cbuf + 16384;                     // 32768 f32
    unsigned*       cnt  = (unsigned*)(Stk + 32768);         // N
    unsigned*       cur  = cnt + N;                          // N
    uint4*          rec  = (uint4*)(cur + N);
    rec = (uint4*)(((size_t)rec + 15) & ~(size_t)15);
    size_t need_sort = (size_t)((char*)(rec + E) - (char*)d_ws);
    const bool tierA = (ws_size >= need_sort);

    // weights prep
    prep_w<<<dim3(16), dim3(256), 0, stream>>>(Wm1, W1f, 8);
    compose_k<<<dim3(64), dim3(256), 0, stream>>>(Wm2, Wg + 128 * 128, Cbuf);
    bias_comp_k<<<dim3(1), dim3(128), 0, stream>>>(bm2, Wg + 128 * 128, bcg);
    stack_k<<<dim3(128), dim3(256), 0, stream>>>(Wg, Cbuf, Stk);
    prep_w_split<<<dim3(16), dim3(256), 0, stream>>>(Stk, WgH, WgL, 8);
    compose_k<<<dim3(64), dim3(256), 0, stream>>>(Wm2, Wu1 + 128 * 128, Cbuf);
    bias_comp_k<<<dim3(1), dim3(128), 0, stream>>>(bm2, Wu1 + 128 * 128, bcu);
    stack_k<<<dim3(128), dim3(256), 0, stream>>>(Wu1, Cbuf, Stk);
    prep_w_split<<<dim3(16), dim3(256), 0, stream>>>(Stk, Wu1H, Wu1L, 8);
    prep_w_split<<<dim3(8), dim3(256), 0, stream>>>(Wu2, Wu2H, Wu2L, 4);

    // dense per-node S1/T
    s1t_gemm<<<dim3((N + 63) / 64), dim3(256), 0, stream>>>(x, W1f, S1b, Tb, N);

    // degree histogram
    hipMemsetAsync(cnt, 0, (size_t)N * sizeof(unsigned), stream);
    hist_k<<<dim3((E + 255) / 256), dim3(256), 0, stream>>>(ei, cnt, E);

    if (tierA) {
        scan_k<<<dim3(1), dim3(1024), 0, stream>>>(cnt, cur, N);
        scatter_k<<<dim3((E + 255) / 256), dim3(256), 0, stream>>>(ei, ea, cur, rec, E);
        csr_edge_k<<<dim3(2048), dim3(256), 0, stream>>>(
            S1b, Tb, rec, cnt, cur, Wm1 + 256 * HID, bm1, HS, N);
    } else {
        hipMemsetAsync(HS, 0, (size_t)N * HID * sizeof(float), stream);
        atomic_edge_k<<<dim3(2048), dim3(256), 0, stream>>>(
            S1b, Tb, ei, ea, Wm1 + 256 * HID, bm1, HS, E);
    }

    int ntilesN = (N + 15) / 16;
    node_mfma<<<dim3((ntilesN + 3) / 4), dim3(256), 0, stream>>>(
        x, HS, cnt, bcg, bcu,
        WgH, WgL, Wu1H, Wu1L, Wu2H, Wu2L,
        bg, bu1, bu2, gmma, beta, out, N);
}